// Round 11
// baseline (231.886 us; speedup 1.0000x reference)
//
#include <hip/hip_runtime.h>
#include <hip/hip_bf16.h>

// ---------------- problem constants ----------------
#define B_TOTAL   32768
#define L_SITES   256
#define N_MID     254        // L-2 middle sites
#define HALF_PI_F 1.57079632679489662f
#define EPS_NORM  1e-8f

// ---------------- ws layout (float/dword slots) ----------------
// [WS_FRAG .. +520191]  A-operand fragment table: 254 steps x 8 frags x 64 lanes x 4 dwords
//                       frag q = h*4 + kh*2 + p  (h: c-half, kh: feature, p: 0=hi,1=lo)
//                       contraction axis PI-PERMUTED (k-slot (quad,j) holds
//                       a = (j<4 ? quad*4+j : 16+quad*4+j-4)) so the swapped-MFMA
//                       output feeds the next step with no transpose.
// [WS_C0   .. +63]      core0 fp32  [f][32]
// [WS_CN   .. +639]     coreN fp32  [f][a][10]
// [WS_X    .. +8388607] xT fp32 [L][B]  (transposed)
// [WS_FLAG]             u32 flag: 1 = inputs are bf16, 0 = fp32
#define WS_FRAG 0
#define WS_C0   520192
#define WS_CN   520256
#define WS_X    520896
#define WS_FLAG 8909504

typedef short bf16x8 __attribute__((ext_vector_type(8)));
typedef float f32x4  __attribute__((ext_vector_type(4)));

// pi-permutation of the contraction axis (k-slot -> actual a index)
__device__ __host__ __forceinline__ int pi_perm(int quad, int j) {
    return (j < 4) ? (quad * 4 + j) : (16 + quad * 4 + (j - 4));
}

__device__ __forceinline__ unsigned short f2bf(float f) {
    unsigned u = __builtin_bit_cast(unsigned, f);
    u += 0x7FFFu + ((u >> 16) & 1u);          // RNE
    return (unsigned short)(u >> 16);
}
__device__ __forceinline__ float bf2f(unsigned short h) {
    unsigned u = ((unsigned)h) << 16;
    return __builtin_bit_cast(float, u);
}
__device__ __forceinline__ bf16x8 asbf(uint4 u) {
    return __builtin_bit_cast(bf16x8, u);
}
// polynomial sincos for sin(pi/2 x), cos(pi/2 x), x in [0,1].
// Taylor through x^11 / x^12: truncation <= 6e-8. 13 FMA + 2 mul, branch-free.
__device__ __forceinline__ void psincos(float x, float* s, float* c) {
    float u = x * x;
    float sp = fmaf(u, -3.5988432352121e-6f, 1.6044118478736e-4f);
    sp = fmaf(u, sp, -4.6817541353187e-3f);
    sp = fmaf(u, sp, 7.9692626246167e-2f);
    sp = fmaf(u, sp, -6.4596409750625e-1f);
    sp = fmaf(u, sp, 1.5707963267949f);
    *s = x * sp;
    float cp = fmaf(u, 4.7108749076366e-7f, -2.5202042373061e-5f);
    cp = fmaf(u, cp, 9.1926027483943e-4f);
    cp = fmaf(u, cp, -2.0863480763353e-2f);
    cp = fmaf(u, cp, 2.5366950790105e-1f);
    cp = fmaf(u, cp, -1.2337005501362f);
    *c = fmaf(u, cp, 1.0f);
}
// packed RNE f32x2 -> bf16x2 (lowers to v_cvt_pk_bf16_f32)
__device__ __forceinline__ unsigned pkbf2(float a, float b) {
    float2 p; p.x = a; p.y = b;
    __hip_bfloat162 h2 = __float22bfloat162_rn(p);
    unsigned u;
    __builtin_memcpy(&u, &h2, 4);
    return u;                                  // a in bits 0..15, b in 16..31
}
// split 8 fp32 into hi/lo bf16 fragments via packed cvt (RNE, proven)
__device__ __forceinline__ void split8(const float* v, bf16x8& hi, bf16x8& lo) {
    uint4 H, L;
    unsigned* hp = (unsigned*)&H;
    unsigned* lp = (unsigned*)&L;
    #pragma unroll
    for (int d = 0; d < 4; ++d) {
        float a = v[2 * d], b = v[2 * d + 1];
        unsigned hb = pkbf2(a, b);
        float h0 = __builtin_bit_cast(float, hb << 16);
        float h1 = __builtin_bit_cast(float, hb & 0xFFFF0000u);
        hp[d] = hb;
        lp[d] = pkbf2(a - h0, b - h1);         // exact residuals
    }
    hi = __builtin_bit_cast(bf16x8, H);
    lo = __builtin_bit_cast(bf16x8, L);
}
// per-wave input-dtype flag: bf16 pairs always have low16 < 0x4000
__device__ __forceinline__ bool detect_bf16(const unsigned* x_raw, int lane) {
    unsigned v = x_raw[lane];
    return __ballot((v & 0xFFFFu) >= 0x4000u) == 0ull;
}

// ---------------- fused aux kernel (r7, unchanged) ----------------
__global__ __launch_bounds__(256)
void aux_all(const void* __restrict__ x_in, const void* __restrict__ c0_in,
             const void* __restrict__ am_in, const void* __restrict__ cn_in,
             float* __restrict__ ws) {
    const int lane = threadIdx.x & 63;
    const bool bf = detect_bf16((const unsigned*)x_in, lane);
    const int b = blockIdx.x;

    if (b < 2048) {
        __shared__ float tile[64][65];          // tile[b_local][l_local], +1 pad
        const int bb = (b & 511) * 64;
        const int ll = (b >> 9) * 64;
        if (!bf) {
            const float4* x4 = (const float4*)x_in;   // row = 64 float4
            const int tr = threadIdx.x >> 4;    // 0..15
            const int q  = threadIdx.x & 15;    // 0..15
            #pragma unroll
            for (int u = 0; u < 4; ++u) {
                int row = tr + u * 16;
                float4 v = x4[(size_t)(bb + row) * (L_SITES / 4) + (ll / 4) + q];
                tile[row][q * 4 + 0] = v.x;
                tile[row][q * 4 + 1] = v.y;
                tile[row][q * 4 + 2] = v.z;
                tile[row][q * 4 + 3] = v.w;
            }
        } else {
            const uint4* x8 = (const uint4*)x_in;     // row = 32 uint4 (8 bf16 each)
            const int tr = threadIdx.x >> 3;    // 0..31
            const int q  = threadIdx.x & 7;     // 0..7
            #pragma unroll
            for (int u = 0; u < 2; ++u) {
                int row = tr + u * 32;
                uint4 v = x8[(size_t)(bb + row) * (L_SITES / 8) + (ll / 8) + q];
                const unsigned short* e = (const unsigned short*)&v;
                #pragma unroll
                for (int k = 0; k < 8; ++k) tile[row][q * 8 + k] = bf2f(e[k]);
            }
        }
        __syncthreads();
        {
            const int tr = threadIdx.x >> 4;    // 0..15
            const int q  = threadIdx.x & 15;    // 0..15
            float4* o4 = (float4*)(ws + WS_X);
            #pragma unroll
            for (int u = 0; u < 4; ++u) {
                int site = tr + u * 16;         // l_local
                float4 v;
                v.x = tile[q * 4 + 0][site];
                v.y = tile[q * 4 + 1][site];
                v.z = tile[q * 4 + 2][site];
                v.w = tile[q * 4 + 3][site];
                o4[((size_t)(ll + site) * B_TOTAL + bb) / 4 + q] = v;
            }
        }
    } else if (b < 2048 + N_MID) {
        const int t = b - 2048;
        __shared__ float amS[2][32][33];        // [f][a][m], +1 pad vs 4-way conflicts
        if (!bf) {
            const float* src = (const float*)am_in + (size_t)t * 2048;
            for (int idx = threadIdx.x; idx < 2048; idx += 256) {
                amS[idx >> 10][(idx >> 5) & 31][idx & 31] = src[idx];
            }
        } else {
            const unsigned short* src = (const unsigned short*)am_in + (size_t)t * 2048;
            for (int idx = threadIdx.x; idx < 2048; idx += 256) {
                amS[idx >> 10][(idx >> 5) & 31][idx & 31] = bf2f(src[idx]);
            }
        }
        __syncthreads();
        #pragma unroll
        for (int u = 0; u < 2; ++u) {
            const int oi = threadIdx.x + 256 * u;   // 0..511
            const int q  = oi >> 6;                 // frag 0..7
            const int l  = oi & 63;                 // lane
            const int h  = q >> 2;
            const int kh = (q >> 1) & 1;
            const int p  = q & 1;
            const int m  = h * 16 + (l & 15);
            const int kb = (l >> 4) * 8;
            unsigned dw[4];
            #pragma unroll
            for (int d = 0; d < 4; ++d) {
                unsigned e01[2];
                #pragma unroll
                for (int s = 0; s < 2; ++s) {
                    int k = kb + 2 * d + s;         // k-slot 0..31
                    int a = pi_perm(k >> 3, k & 7); // PI-permuted contraction index
                    float v = amS[kh][a][m];
                    unsigned short hi = f2bf(v);
                    e01[s] = (p == 0) ? hi : f2bf(v - bf2f(hi));
                }
                dw[d] = e01[0] | (e01[1] << 16);
            }
            uint4 o; o.x = dw[0]; o.y = dw[1]; o.z = dw[2]; o.w = dw[3];
            ((uint4*)ws)[(size_t)(t * 8 + q) * 64 + l] = o;
        }
    } else {
        for (int i = threadIdx.x; i < 640; i += 256) {
            if (i < 64)
                ws[WS_C0 + i] = bf ? bf2f(((const unsigned short*)c0_in)[i])
                                   : ((const float*)c0_in)[i];
            ws[WS_CN + i] = bf ? bf2f(((const unsigned short*)cn_in)[i])
                               : ((const float*)cn_in)[i];
        }
        if (threadIdx.x == 0)
            *(unsigned*)(ws + WS_FLAG) = bf ? 1u : 0u;
    }
}

// ---------------- main chain kernel ----------------
// r4/r7 step math (swapped-operand chain, post-scale factorization, bit-exact)
// + asm-pinned frag prefetch, SPILL-SAFE variant:
//  * r9/r10 both corrupted (~0.70) regardless of wait scheme -> the hole is
//    SPILLS: a spill-store of an asm-load destination executes right after
//    issue (before any waitcnt) and stores garbage to scratch. Fix:
//    __launch_bounds__(256,2) raises the VGPR budget to 256 (live set ~130,
//    no spills) and the x-loads go back to plain C++ (smaller pinned set;
//    extra compiler VMEM is harmless under vmcnt(0) waits).
//  * robust wait: vmcnt(0) at the TOP of each half-step, BEFORE issuing the
//    next batch — zero counting assumptions, one-full-step prefetch distance.
//  * sched_barrier(0) after each wait (rule #18).
//  * polynomial sincos (~14 VALU vs ocml ~60).
__global__ __launch_bounds__(256, 2)
void mps_mfma(const float* __restrict__ ws, void* __restrict__ out) {
    const int lane = threadIdx.x & 63;
    const int w    = threadIdx.x >> 6;
    const int r    = lane & 15;
    const int quad = lane >> 4;
    const int b0   = (blockIdx.x * 4 + w) * 16;
    const float* __restrict__ xT = ws + WS_X;
    const uint4* __restrict__ BF = (const uint4*)ws;   // WS_FRAG = 0
    const int i = b0 + r;

// issue one batch: 8 frag dwordx4 for step STEP (asm-pinned, cannot be sunk)
#define ISSUE_BATCH(F, STEP)                                                       \
    {                                                                              \
        const uint4* bA_ = BF + (size_t)(STEP) * 512 + lane;                       \
        const uint4* bB_ = bA_ + 256;                                              \
        asm volatile("global_load_dwordx4 %0, %1, off"             : "=v"((F)[0]) : "v"(bA_) : "memory"); \
        asm volatile("global_load_dwordx4 %0, %1, off offset:1024" : "=v"((F)[1]) : "v"(bA_) : "memory"); \
        asm volatile("global_load_dwordx4 %0, %1, off offset:2048" : "=v"((F)[2]) : "v"(bA_) : "memory"); \
        asm volatile("global_load_dwordx4 %0, %1, off offset:3072" : "=v"((F)[3]) : "v"(bA_) : "memory"); \
        asm volatile("global_load_dwordx4 %0, %1, off"             : "=v"((F)[4]) : "v"(bB_) : "memory"); \
        asm volatile("global_load_dwordx4 %0, %1, off offset:1024" : "=v"((F)[5]) : "v"(bB_) : "memory"); \
        asm volatile("global_load_dwordx4 %0, %1, off offset:2048" : "=v"((F)[6]) : "v"(bB_) : "memory"); \
        asm volatile("global_load_dwordx4 %0, %1, off offset:3072" : "=v"((F)[7]) : "v"(bB_) : "memory"); \
    }

// robust wait: everything outstanding (= previous batch + any other VMEM) done
#define WAIT_ALL                                                                   \
    asm volatile("s_waitcnt vmcnt(0)" ::: "memory");                               \
    __builtin_amdgcn_sched_barrier(0)

// one chain step: split M once -> 12 MFMA (4 indep 3-chains) -> post-scale
// combine with (CT,ST) -> optional norm.  (bit-identical to r7)
#define DO_STEP(CT, ST, F, DONORM)                                                 \
    {                                                                              \
        bf16x8 mh, ml;                                                             \
        split8(mm, mh, ml);                                                        \
        const f32x4 z = {0.f, 0.f, 0.f, 0.f};                                      \
        __builtin_amdgcn_s_setprio(1);                                             \
        f32x4 p00 = __builtin_amdgcn_mfma_f32_16x16x32_bf16(asbf((F)[0]), mh, z, 0, 0, 0);    \
        f32x4 p01 = __builtin_amdgcn_mfma_f32_16x16x32_bf16(asbf((F)[2]), mh, z, 0, 0, 0);    \
        f32x4 p10 = __builtin_amdgcn_mfma_f32_16x16x32_bf16(asbf((F)[4]), mh, z, 0, 0, 0);    \
        f32x4 p11 = __builtin_amdgcn_mfma_f32_16x16x32_bf16(asbf((F)[6]), mh, z, 0, 0, 0);    \
        p00 = __builtin_amdgcn_mfma_f32_16x16x32_bf16(asbf((F)[1]), mh, p00, 0, 0, 0); \
        p01 = __builtin_amdgcn_mfma_f32_16x16x32_bf16(asbf((F)[3]), mh, p01, 0, 0, 0); \
        p10 = __builtin_amdgcn_mfma_f32_16x16x32_bf16(asbf((F)[5]), mh, p10, 0, 0, 0); \
        p11 = __builtin_amdgcn_mfma_f32_16x16x32_bf16(asbf((F)[7]), mh, p11, 0, 0, 0); \
        p00 = __builtin_amdgcn_mfma_f32_16x16x32_bf16(asbf((F)[0]), ml, p00, 0, 0, 0); \
        p01 = __builtin_amdgcn_mfma_f32_16x16x32_bf16(asbf((F)[2]), ml, p01, 0, 0, 0); \
        p10 = __builtin_amdgcn_mfma_f32_16x16x32_bf16(asbf((F)[4]), ml, p10, 0, 0, 0); \
        p11 = __builtin_amdgcn_mfma_f32_16x16x32_bf16(asbf((F)[6]), ml, p11, 0, 0, 0); \
        __builtin_amdgcn_s_setprio(0);                                             \
        _Pragma("unroll")                                                          \
        for (int j = 0; j < 4; ++j) {                                              \
            mm[j]     = fmaf((ST), p01[j], (CT) * p00[j]);                         \
            mm[4 + j] = fmaf((ST), p11[j], (CT) * p10[j]);                         \
        }                                                                          \
        if (DONORM) {                                                              \
            float ss = 0.f;                                                        \
            _Pragma("unroll")                                                      \
            for (int j = 0; j < 8; ++j) ss = fmaf(mm[j], mm[j], ss);               \
            ss += __shfl_xor(ss, 16);                                              \
            ss += __shfl_xor(ss, 32);                                              \
            float kk = 1.0f / (sqrtf(ss) + EPS_NORM);                              \
            _Pragma("unroll")                                                      \
            for (int j = 0; j < 8; ++j) mm[j] *= kk;                               \
        }                                                                          \
    }

    // ---- prologue: issue batch for step 0 FIRST (cover = M0 compute) ----
    uint4 FA[8], FB[8];
    ISSUE_BATCH(FA, 0)

    // ---- M0 in pi-layout: mm[j] = M0[b=r][a=pi(quad,j)] ----
    float mm[8];
    {
        float x0 = xT[i];
        float sn, cs; psincos(x0, &sn, &cs);
        const float* c0 = ws + WS_C0;
        #pragma unroll
        for (int j = 0; j < 8; ++j) {
            int a = pi_perm(quad, j);
            mm[j] = cs * c0[a] + sn * c0[32 + a];
        }
    }
    float ct0, st0;                                     // factors for step 0 (site 1)
    { float xc = xT[(size_t)B_TOTAL + i]; psincos(xc, &st0, &ct0); }
    float ct1, st1;

    #pragma unroll 1
    for (int t = 0; t < N_MID; t += 2) {
        // ======== even step t ========
        WAIT_ALL;                                       // FA batch landed (robust)
        ISSUE_BATCH(FB, t + 1)                          // t+1 <= 253: valid
        { float xv = xT[(size_t)(t + 2) * B_TOTAL + i]; // x for step t+1 (site t+2 <= 254)
          psincos(xv, &st1, &ct1); }
        DO_STEP(ct0, st0, FA, false)                    // FB in flight under this step

        // ======== odd step t+1 ========
        WAIT_ALL;                                       // FB batch landed (robust)
        if (t + 2 < N_MID) {
            ISSUE_BATCH(FA, t + 2)                      // valid
        }
        { float xv = xT[(size_t)(t + 3) * B_TOTAL + i]; // x for step t+2 (site t+3 <= 255)
          psincos(xv, &st0, &ct0); }
        DO_STEP(ct1, st1, FB, (((t + 1) & 7) == 7) || (t + 1 == N_MID - 1))
    }
    // last iteration issued nothing in the odd half -> nothing in flight here
#undef DO_STEP
#undef WAIT_ALL
#undef ISSUE_BATCH

    // ---- readout: logits[r][c] = sum_a M[r][a]*(cN*KN0[a,c] + sN*KN1[a,c]) ----
    {
        float xN = xT[(size_t)(L_SITES - 1) * B_TOTAL + i];
        float sN, cN; psincos(xN, &sN, &cN);
        const float* kn = ws + WS_CN;        // [f][a][10]
        float acc[10];
        #pragma unroll
        for (int c = 0; c < 10; ++c) acc[c] = 0.f;
        #pragma unroll
        for (int j = 0; j < 8; ++j) {
            int a = pi_perm(quad, j);
            float Ma = mm[j];
            #pragma unroll
            for (int c = 0; c < 10; ++c) {
                float fin = cN * kn[a * 10 + c] + sN * kn[320 + a * 10 + c];
                acc[c] = fmaf(Ma, fin, acc[c]);
            }
        }
        #pragma unroll
        for (int c = 0; c < 10; ++c) {
            acc[c] += __shfl_xor(acc[c], 16);
            acc[c] += __shfl_xor(acc[c], 32);
        }
        const unsigned bf = *(const unsigned*)(ws + WS_FLAG);
        if (quad == 0) {
            if (bf) {
                __hip_bfloat16* o = (__hip_bfloat16*)out;
                #pragma unroll
                for (int c = 0; c < 10; ++c)
                    o[(size_t)(b0 + r) * 10 + c] = __float2bfloat16(acc[c]);
            } else {
                float* o = (float*)out;
                #pragma unroll
                for (int c = 0; c < 10; ++c)
                    o[(size_t)(b0 + r) * 10 + c] = acc[c];
            }
        }
    }
}

// ---------------- launch ----------------
extern "C" void kernel_launch(void* const* d_in, const int* in_sizes, int n_in,
                              void* d_out, int out_size, void* d_ws, size_t ws_size,
                              hipStream_t stream) {
    float* ws = (float*)d_ws;
    aux_all<<<2048 + N_MID + 1, 256, 0, stream>>>(d_in[0], d_in[1], d_in[2], d_in[3], ws);
    // 512 blocks x 4 waves x 16 samples = 32768 samples; 2048 waves = 2 waves/SIMD
    mps_mfma<<<512, 256, 0, stream>>>(ws, d_out);
}